// Round 1
// baseline (166.456 us; speedup 1.0000x reference)
//
#include <hip/hip_runtime.h>
#include <hip/hip_bf16.h>

#define NROWS 131072
#define DK    1024
#define CCLS  21
#define CTF   84
#define NCOL  105         // 21 + 84
#define NKT   (DK/32)     // 32 k-tiles of 32
#define NCT   7           // 112 padded cols / 16

#define BM    128
#define LDA   40          // LDS row stride in bf16 (32 used + 8 pad -> no bank conflicts)

typedef __attribute__((ext_vector_type(4))) float f32x4;
typedef __attribute__((ext_vector_type(8))) short bf16x8;
typedef __attribute__((ext_vector_type(4))) short bf16x4;

__device__ __forceinline__ unsigned short f2bf(float x) {
    union { float f; unsigned u; } v; v.f = x;
    unsigned r = v.u + 0x7fffu + ((v.u >> 16) & 1u);   // RNE
    return (unsigned short)(r >> 16);
}

// Pack [W_cls | W_tf | zero-pad] into bf16 MFMA B-fragment order:
// element ((kt*NCT + ct)*64 + lane)*8 + j  holds  B[k][col]
//   col = ct*16 + (lane&15),  k = kt*32 + (lane>>4)*8 + j
__global__ void pack_B_kernel(const float* __restrict__ Wc,
                              const float* __restrict__ Wt,
                              unsigned short* __restrict__ Bp) {
    const int frag = blockIdx.x;           // kt*NCT + ct, 224 total
    const int kt = frag / NCT, ct = frag % NCT;
    const int lane = threadIdx.x;          // 64
    const int col = ct * 16 + (lane & 15);
    const int k0  = kt * 32 + ((lane >> 4) << 3);
    bf16x8 o;
#pragma unroll
    for (int j = 0; j < 8; ++j) {
        const int k = k0 + j;
        float v = 0.0f;
        if (col < CCLS)      v = Wc[k * CCLS + col];
        else if (col < NCOL) v = Wt[k * CTF + (col - CCLS)];
        o[j] = (short)f2bf(v);
    }
    *reinterpret_cast<bf16x8*>(Bp + ((size_t)frag * 64 + lane) * 8) = o;
}

__global__ __launch_bounds__(256)
void roi_gemm_kernel(const float* __restrict__ F,
                     const unsigned short* __restrict__ Bp,
                     const float* __restrict__ bcls,
                     const float* __restrict__ btf,
                     float* __restrict__ out) {
    __shared__ unsigned short Alds[2][BM * LDA];

    const int t    = threadIdx.x;
    const int wave = t >> 6;
    const int lane = t & 63;
    const long row0 = (long)blockIdx.x * BM;

    // staging: thread t covers rows srow+32*i (i=0..3), f32 cols scol..scol+3
    const int srow = t >> 3;               // 0..31
    const int scol = (t & 7) * 4;

    // fragment addressing
    const int fr = lane & 15;              // A row within 16-tile / C col
    const int fk = (lane >> 4) * 8;        // k offset within 32

    f32x4 acc[2][NCT];
#pragma unroll
    for (int a = 0; a < 2; ++a)
#pragma unroll
        for (int b = 0; b < NCT; ++b)
            acc[a][b] = (f32x4){0.f, 0.f, 0.f, 0.f};

    const float* Fb = F + (size_t)row0 * DK;

    // prologue: stage k-tile 0 into buffer 0
#pragma unroll
    for (int i = 0; i < 4; ++i) {
        const f32x4 v = *reinterpret_cast<const f32x4*>(Fb + (size_t)(srow + 32 * i) * DK + scol);
        bf16x4 w;
#pragma unroll
        for (int j = 0; j < 4; ++j) w[j] = (short)f2bf(v[j]);
        *reinterpret_cast<bf16x4*>(&Alds[0][(srow + 32 * i) * LDA + scol]) = w;
    }
    __syncthreads();

    for (int kt = 0; kt < NKT; ++kt) {
        const int cur = kt & 1;

        // issue next A-tile global loads early (hide HBM latency under MFMA)
        f32x4 nx[4];
        if (kt + 1 < NKT) {
#pragma unroll
            for (int i = 0; i < 4; ++i)
                nx[i] = *reinterpret_cast<const f32x4*>(
                    Fb + (size_t)(srow + 32 * i) * DK + (size_t)(kt + 1) * 32 + scol);
        }

        // B fragments straight from global (L2-resident, lane-contiguous 16B)
        bf16x8 bfrag[NCT];
        const unsigned short* bb = Bp + ((size_t)kt * NCT * 64 + lane) * 8;
#pragma unroll
        for (int ct = 0; ct < NCT; ++ct)
            bfrag[ct] = *reinterpret_cast<const bf16x8*>(bb + (size_t)ct * 64 * 8);

        // A fragments from LDS
        bf16x8 afrag[2];
#pragma unroll
        for (int rt = 0; rt < 2; ++rt) {
            const int r = wave * 32 + rt * 16 + fr;
            afrag[rt] = *reinterpret_cast<const bf16x8*>(&Alds[cur][r * LDA + fk]);
        }

#pragma unroll
        for (int rt = 0; rt < 2; ++rt)
#pragma unroll
            for (int ct = 0; ct < NCT; ++ct)
                acc[rt][ct] = __builtin_amdgcn_mfma_f32_16x16x32_bf16(
                    afrag[rt], bfrag[ct], acc[rt][ct], 0, 0, 0);

        // convert + write next tile into the other buffer
        if (kt + 1 < NKT) {
#pragma unroll
            for (int i = 0; i < 4; ++i) {
                bf16x4 w;
#pragma unroll
                for (int j = 0; j < 4; ++j) w[j] = (short)f2bf(nx[i][j]);
                *reinterpret_cast<bf16x4*>(&Alds[cur ^ 1][(srow + 32 * i) * LDA + scol]) = w;
            }
        }
        __syncthreads();
    }

    // epilogue: bias + scatter into the two outputs
    float* out_tf = out + (size_t)NROWS * CCLS;
#pragma unroll
    for (int rt = 0; rt < 2; ++rt) {
        const long rbase = row0 + wave * 32 + rt * 16 + ((lane >> 4) << 2);
#pragma unroll
        for (int ct = 0; ct < NCT; ++ct) {
            const int col = ct * 16 + (lane & 15);
            if (col >= NCOL) continue;
            const float bias = (col < CCLS) ? bcls[col] : btf[col - CCLS];
#pragma unroll
            for (int j = 0; j < 4; ++j) {
                const long row = rbase + j;
                const float v = acc[rt][ct][j] + bias;
                if (col < CCLS) out[row * CCLS + col] = v;
                else            out_tf[row * CTF + (col - CCLS)] = v;
            }
        }
    }
}

extern "C" void kernel_launch(void* const* d_in, const int* in_sizes, int n_in,
                              void* d_out, int out_size, void* d_ws, size_t ws_size,
                              hipStream_t stream) {
    const float* F  = (const float*)d_in[0];
    const float* Wc = (const float*)d_in[1];
    const float* bc = (const float*)d_in[2];
    const float* Wt = (const float*)d_in[3];
    const float* bt = (const float*)d_in[4];
    unsigned short* Bp = (unsigned short*)d_ws;   // needs 229,376 B

    pack_B_kernel<<<NKT * NCT, 64, 0, stream>>>(Wc, Wt, Bp);
    roi_gemm_kernel<<<NROWS / BM, 256, 0, stream>>>(F, Bp, bc, bt, (float*)d_out);
}